// Round 11
// baseline (559.346 us; speedup 1.0000x reference)
//
#include <hip/hip_runtime.h>
#include <hip/hip_bf16.h>
#include <stdint.h>

// CrystalGraphEncoder on MI355X — round 11:
//  R10 post-mortem: fused-mm cost ~0 (LAST dispatch, no mm, also 138us) but
//  4-serial-atoms-per-wave + __syncthreads straggler = 2.5x agg regression.
//  R11: R7 agg structure restored (1 atom/wave, 4-deep, no barrier) + PER-WAVE
//  fused mm: shfl x into A-frag (all rows identical -> every lane valid),
//  24 MFMAs vs wprep, kg==0 lanes store. sched_barrier(0) splits reg lifetimes.
//  LAST: grid-stride 2048 blocks + LDS pool partial. x array deleted.
//  11 dispatches.
//
// ws: grA|grB bf16 | glpkA|glpkB u32 | ebuf | cols | offs | bcnt/bstart/bcur
//     | wprep | bgs | pool  (~85 MB)

#define H 64
#define BSHIFT 6
#define BROWS 64
#define NLOG2E -1.4426950408889634f

typedef __attribute__((ext_vector_type(8))) short bf16x8;
typedef __attribute__((ext_vector_type(4))) float f32x4;

__device__ __forceinline__ ushort f2bf(float f) {  // RNE
  uint32_t u = __float_as_uint(f);
  u = (u + 0x7fffu + ((u >> 16) & 1u)) >> 16;
  return (ushort)u;
}
__device__ __forceinline__ uint32_t pack_gl(float gc, float lin) {
  uint32_t ug = __float_as_uint(gc);
  ug = (ug + 0x7fffu + ((ug >> 16) & 1u)) >> 16;
  uint32_t ul = __float_as_uint(lin);
  ul = ((ul + 0x7fffu + ((ul >> 16) & 1u)) >> 16) << 16;
  return ul | ug;
}
__device__ __forceinline__ float unpack_gc(uint32_t p) {
  return __uint_as_float(p << 16);
}
__device__ __forceinline__ float unpack_lin(uint32_t p) {
  return __uint_as_float(p & 0xffff0000u);
}
__device__ __forceinline__ float sig_from_neglog2(float arg) {
  return __builtin_amdgcn_rcpf(1.f + exp2f(arg));
}

// ---------- prep ----------
__global__ __launch_bounds__(256) void prep_kernel(
    const float* __restrict__ Wl, const float* __restrict__ Wg,
    const float* __restrict__ bg, bf16x8* __restrict__ wprep,
    float* __restrict__ bgs) {
  const int t = blockIdx.x * 256 + threadIdx.x;
  if (t < 192) bgs[t] = bg[t] * NLOG2E;
  if (t >= 4608) return;
  const int l = t / 1536;
  const int rem = t - l * 1536;
  const int mat = rem >> 9;
  const int rem2 = rem & 511;
  const int nt = rem2 >> 7;
  const int ks = (rem2 >> 6) & 1;
  const int lane = rem2 & 63;
  const int kg = lane >> 4, l15 = lane & 15;
  const float* src;
  float s;
  if (mat == 0)      { src = Wl + (size_t)l * 4096;        s = 1.f; }
  else if (mat == 1) { src = Wg + (size_t)l * 8192;        s = NLOG2E; }
  else               { src = Wg + (size_t)l * 8192 + 4096; s = NLOG2E; }
  bf16x8 v;
#pragma unroll
  for (int j = 0; j < 8; j++)
    v[j] = (short)f2bf(src[(size_t)(ks * 32 + kg * 8 + j) * 64 + nt * 16 + l15] * s);
  wprep[t] = v;
}

// ---------- bucket hist / scan / scatter / csr (R10, measured ~24us chain) ----------
__global__ __launch_bounds__(256) void bucket_hist_kernel(
    const int* __restrict__ row, int* __restrict__ bcnt, int E, int nbuck) {
  __shared__ int cnt[2048];
  const int tid = threadIdx.x;
  for (int b = tid; b < nbuck; b += 256) cnt[b] = 0;
  __syncthreads();
  for (int e = blockIdx.x * blockDim.x + tid; e < E; e += gridDim.x * blockDim.x)
    atomicAdd(&cnt[row[e] >> BSHIFT], 1);
  __syncthreads();
  for (int b = tid; b < nbuck; b += 256)
    if (cnt[b]) atomicAdd(&bcnt[b], cnt[b]);
}

__global__ __launch_bounds__(1024) void bucket_scan_kernel(
    const int* __restrict__ bcnt, int* __restrict__ bstart,
    int* __restrict__ bcur, int* __restrict__ offs, float* __restrict__ pool,
    int nbuck, int N, int E) {
  __shared__ int sh[1024];
  const int tid = threadIdx.x;
  if (tid < 64) pool[tid] = 0.f;
  const int i0 = 2 * tid, i1 = 2 * tid + 1;
  const int v0 = (i0 < nbuck) ? bcnt[i0] : 0;
  const int v1 = (i1 < nbuck) ? bcnt[i1] : 0;
  const int s = v0 + v1;
  sh[tid] = s;
  __syncthreads();
  for (int off = 1; off < 1024; off <<= 1) {
    const int v = (tid >= off) ? sh[tid - off] : 0;
    __syncthreads();
    sh[tid] += v;
    __syncthreads();
  }
  const int ex = sh[tid] - s;
  if (i0 < nbuck) { bstart[i0] = ex;      bcur[i0] = ex; }
  if (i1 < nbuck) { bstart[i1] = ex + v0; bcur[i1] = ex + v0; }
  if (tid == 0) { bstart[nbuck] = E; offs[N] = E; }
}

#define SCHUNK 4096
__global__ __launch_bounds__(256) void bucket_scatter_kernel(
    const int* __restrict__ row, const int* __restrict__ col,
    int* __restrict__ bcur, uint32_t* __restrict__ ebuf, int E, int nbuck) {
  __shared__ int cnt[2048], base[2048];
  const int tid = threadIdx.x;
  const int start = blockIdx.x * SCHUNK;
  const int end = min(start + SCHUNK, E);
  for (int b = tid; b < nbuck; b += 256) cnt[b] = 0;
  __syncthreads();
  for (int e = start + tid; e < end; e += 256)
    atomicAdd(&cnt[row[e] >> BSHIFT], 1);
  __syncthreads();
  for (int b = tid; b < nbuck; b += 256) {
    if (cnt[b]) base[b] = atomicAdd(&bcur[b], cnt[b]);
    cnt[b] = 0;
  }
  __syncthreads();
  for (int e = start + tid; e < end; e += 256) {
    const int r = row[e];
    const int b = r >> BSHIFT;
    const int pos = base[b] + atomicAdd(&cnt[b], 1);
    ebuf[pos] = ((uint32_t)(r & (BROWS - 1)) << 26) | (uint32_t)col[e];
  }
}

__global__ __launch_bounds__(256) void csr_build_kernel(
    const uint32_t* __restrict__ ebuf, const int* __restrict__ bstart,
    int* __restrict__ offs, int* __restrict__ cols, int N) {
  __shared__ int cnt[BROWS], sc[BROWS];
  const int tid = threadIdx.x;
  const int b = blockIdx.x;
  const int bs = bstart[b], be = bstart[b + 1];
  const int rowbase = b << BSHIFT;
  if (tid < BROWS) cnt[tid] = 0;
  __syncthreads();
  for (int e = bs + tid; e < be; e += 256)
    atomicAdd(&cnt[ebuf[e] >> 26], 1);
  __syncthreads();
  if (tid < BROWS) sc[tid] = cnt[tid];
  __syncthreads();
  for (int off = 1; off < BROWS; off <<= 1) {
    const int v = (tid >= off && tid < BROWS) ? sc[tid - off] : 0;
    __syncthreads();
    if (tid < BROWS) sc[tid] += v;
    __syncthreads();
  }
  if (tid < BROWS) {
    sc[tid] -= cnt[tid];
    cnt[tid] = 0;
    const int r = rowbase + tid;
    if (r < N) offs[r] = bs + sc[tid];
  }
  __syncthreads();
  for (int e = bs + tid; e < be; e += 256) {
    const uint32_t u = ebuf[e];
    const int rl = (int)(u >> 26);
    const int pos = sc[rl] + atomicAdd(&cnt[rl], 1);
    cols[bs + pos] = (int)(u & 0x3FFFFFFu);
  }
}

// ---------- mm0: embed -> layer-0 gr/glpk via MFMA ----------
__global__ __launch_bounds__(256) void node_mm0_mfma(
    const int* __restrict__ an, const float* __restrict__ emb,
    const bf16x8* __restrict__ wp, const float* __restrict__ bl,
    const float* __restrict__ bgs, ushort* __restrict__ gr,
    uint32_t* __restrict__ glpk, int N) {
  const int tid = threadIdx.x;
  const int lane = tid & 63, wid = tid >> 6;
  const int l15 = lane & 15, kg = lane >> 4;

  bf16x8 bfrag[3][4][2];
#pragma unroll
  for (int mat = 0; mat < 3; mat++)
#pragma unroll
    for (int nt = 0; nt < 4; nt++)
#pragma unroll
      for (int ks = 0; ks < 2; ks++)
        bfrag[mat][nt][ks] = wp[(((mat * 4 + nt) * 2 + ks) << 6) + lane];

  const int mbase = blockIdx.x * 64 + wid * 16;
  const int arow_c = min(mbase + l15, N - 1);

  const int a = an[arow_c];
  const float* src = emb + (size_t)a * H + kg * 8;
  const float4 u0 = *(const float4*)(src);
  const float4 u1 = *(const float4*)(src + 4);
  const float4 u2 = *(const float4*)(src + 32);
  const float4 u3 = *(const float4*)(src + 36);
  bf16x8 afrag0, afrag1;
  afrag0[0] = (short)f2bf(u0.x); afrag0[1] = (short)f2bf(u0.y);
  afrag0[2] = (short)f2bf(u0.z); afrag0[3] = (short)f2bf(u0.w);
  afrag0[4] = (short)f2bf(u1.x); afrag0[5] = (short)f2bf(u1.y);
  afrag0[6] = (short)f2bf(u1.z); afrag0[7] = (short)f2bf(u1.w);
  afrag1[0] = (short)f2bf(u2.x); afrag1[1] = (short)f2bf(u2.y);
  afrag1[2] = (short)f2bf(u2.z); afrag1[3] = (short)f2bf(u2.w);
  afrag1[4] = (short)f2bf(u3.x); afrag1[5] = (short)f2bf(u3.y);
  afrag1[6] = (short)f2bf(u3.z); afrag1[7] = (short)f2bf(u3.w);

  f32x4 accL[4], accR[4], accC[4];
#pragma unroll
  for (int nt = 0; nt < 4; nt++) {
    const float blv = bl[nt * 16 + l15];
    const float bgv = bgs[nt * 16 + l15];
    accL[nt] = (f32x4){blv, blv, blv, blv};
    accR[nt] = (f32x4){0.f, 0.f, 0.f, 0.f};
    accC[nt] = (f32x4){bgv, bgv, bgv, bgv};
  }
#pragma unroll
  for (int nt = 0; nt < 4; nt++) {
    accL[nt] = __builtin_amdgcn_mfma_f32_16x16x32_bf16(afrag0, bfrag[0][nt][0], accL[nt], 0, 0, 0);
    accL[nt] = __builtin_amdgcn_mfma_f32_16x16x32_bf16(afrag1, bfrag[0][nt][1], accL[nt], 0, 0, 0);
    accR[nt] = __builtin_amdgcn_mfma_f32_16x16x32_bf16(afrag0, bfrag[1][nt][0], accR[nt], 0, 0, 0);
    accR[nt] = __builtin_amdgcn_mfma_f32_16x16x32_bf16(afrag1, bfrag[1][nt][1], accR[nt], 0, 0, 0);
    accC[nt] = __builtin_amdgcn_mfma_f32_16x16x32_bf16(afrag0, bfrag[2][nt][0], accC[nt], 0, 0, 0);
    accC[nt] = __builtin_amdgcn_mfma_f32_16x16x32_bf16(afrag1, bfrag[2][nt][1], accC[nt], 0, 0, 0);
  }
#pragma unroll
  for (int nt = 0; nt < 4; nt++) {
#pragma unroll
    for (int r = 0; r < 4; r++) {
      const int atom = mbase + kg * 4 + r;
      if (atom < N) {
        const size_t o = (size_t)atom * H + nt * 16 + l15;
        gr[o] = f2bf(accR[nt][r]);
        glpk[o] = pack_gl(accC[nt][r], accL[nt][r]);
      }
    }
  }
}

// ---------- R7-style per-atom aggregate (1 atom per wave, 4-deep) ----------
__device__ __forceinline__ float agg_atom(
    int i, int lane, const ushort* __restrict__ gr,
    const uint32_t* __restrict__ glpk, const int* __restrict__ offs,
    const int* __restrict__ cols) {
  const int s = offs[i], e = offs[i + 1];
  const float gri = __uint_as_float((uint32_t)gr[((size_t)i << 6) | lane] << 16);
  float acc = 0.f;
  for (int cb = s; cb < e; cb += 64) {
    const int nchunk = min(64, e - cb);
    const int myc = (lane < nchunk) ? cols[cb + lane] : 0;
    int j = 0;
    for (; j + 3 < nchunk; j += 4) {
      const int c0 = __shfl(myc, j + 0), c1 = __shfl(myc, j + 1);
      const int c2 = __shfl(myc, j + 2), c3 = __shfl(myc, j + 3);
      const uint32_t p0 = glpk[((size_t)c0 << 6) | lane];
      const uint32_t p1 = glpk[((size_t)c1 << 6) | lane];
      const uint32_t p2 = glpk[((size_t)c2 << 6) | lane];
      const uint32_t p3 = glpk[((size_t)c3 << 6) | lane];
      acc += unpack_lin(p0) * sig_from_neglog2(gri + unpack_gc(p0));
      acc += unpack_lin(p1) * sig_from_neglog2(gri + unpack_gc(p1));
      acc += unpack_lin(p2) * sig_from_neglog2(gri + unpack_gc(p2));
      acc += unpack_lin(p3) * sig_from_neglog2(gri + unpack_gc(p3));
    }
    for (; j < nchunk; j++) {
      const int c0 = __shfl(myc, j);
      const uint32_t p0 = glpk[((size_t)c0 << 6) | lane];
      acc += unpack_lin(p0) * sig_from_neglog2(gri + unpack_gc(p0));
    }
  }
  const float li = unpack_lin(glpk[((size_t)i << 6) | lane]);
  return fmaxf(acc + li, 0.f);
}

// ---------- agg(l) + per-wave mm(l+1): 1 atom/wave, no barriers ----------
__global__ __launch_bounds__(256) void agg_mm_kernel(
    const ushort* __restrict__ gr, const uint32_t* __restrict__ glpk,
    const int* __restrict__ offs, const int* __restrict__ cols,
    const bf16x8* __restrict__ wp, const float* __restrict__ bl,
    const float* __restrict__ bgs, ushort* __restrict__ gr_out,
    uint32_t* __restrict__ glpk_out, int N) {
  const int lane = threadIdx.x & 63, w = threadIdx.x >> 6;
  const int i = blockIdx.x * 4 + w;  // wave-uniform atom
  if (i >= N) return;

  const float v = agg_atom(i, lane, gr, glpk, offs, cols);

  __builtin_amdgcn_sched_barrier(0);  // keep mm regs out of agg region

  // redistribute v (lane=channel) into A-frag; all 16 A-rows identical,
  // so every lane's D[.][l15] is the valid output for col l15.
  const int l15 = lane & 15, kg = lane >> 4;
  bf16x8 a0, a1;
#pragma unroll
  for (int j = 0; j < 8; j++) {
    a0[j] = (short)f2bf(__shfl(v, kg * 8 + j));
    a1[j] = (short)f2bf(__shfl(v, 32 + kg * 8 + j));
  }

  float linv[4];
#pragma unroll
  for (int nt = 0; nt < 4; nt++) {  // mat 0 = lin
    const float b = bl[nt * 16 + l15];
    f32x4 acc = (f32x4){b, b, b, b};
    acc = __builtin_amdgcn_mfma_f32_16x16x32_bf16(a0, wp[(((0 * 4 + nt) * 2 + 0) << 6) + lane], acc, 0, 0, 0);
    acc = __builtin_amdgcn_mfma_f32_16x16x32_bf16(a1, wp[(((0 * 4 + nt) * 2 + 1) << 6) + lane], acc, 0, 0, 0);
    linv[nt] = acc[0];
  }
#pragma unroll
  for (int nt = 0; nt < 4; nt++) {  // mat 2 = gc -> glpk (with lin)
    const float b = bgs[nt * 16 + l15];
    f32x4 acc = (f32x4){b, b, b, b};
    acc = __builtin_amdgcn_mfma_f32_16x16x32_bf16(a0, wp[(((2 * 4 + nt) * 2 + 0) << 6) + lane], acc, 0, 0, 0);
    acc = __builtin_amdgcn_mfma_f32_16x16x32_bf16(a1, wp[(((2 * 4 + nt) * 2 + 1) << 6) + lane], acc, 0, 0, 0);
    if (kg == 0) glpk_out[((size_t)i << 6) | (nt * 16 + l15)] = pack_gl(acc[0], linv[nt]);
  }
#pragma unroll
  for (int nt = 0; nt < 4; nt++) {  // mat 1 = gr
    f32x4 acc = (f32x4){0.f, 0.f, 0.f, 0.f};
    acc = __builtin_amdgcn_mfma_f32_16x16x32_bf16(a0, wp[(((1 * 4 + nt) * 2 + 0) << 6) + lane], acc, 0, 0, 0);
    acc = __builtin_amdgcn_mfma_f32_16x16x32_bf16(a1, wp[(((1 * 4 + nt) * 2 + 1) << 6) + lane], acc, 0, 0, 0);
    if (kg == 0) gr_out[((size_t)i << 6) | (nt * 16 + l15)] = f2bf(acc[0]);
  }
}

// ---------- last layer: agg + pool (grid-stride, per-block LDS partial) ----------
__global__ __launch_bounds__(256) void agg_pool_kernel(
    const ushort* __restrict__ gr, const uint32_t* __restrict__ glpk,
    const int* __restrict__ offs, const int* __restrict__ cols,
    float* __restrict__ pool, int N) {
  __shared__ float pacc[4][64];
  const int lane = threadIdx.x & 63, w = threadIdx.x >> 6;
  float psum = 0.f;
  for (int i = blockIdx.x * 4 + w; i < N; i += gridDim.x * 4)
    psum += agg_atom(i, lane, gr, glpk, offs, cols);
  pacc[w][lane] = psum;
  __syncthreads();
  if (w == 0) {
    const float t = pacc[0][lane] + pacc[1][lane] + pacc[2][lane] + pacc[3][lane];
    atomicAdd(&pool[lane], t);
  }
}

// ---------- final MLP ----------
__global__ void mlp_kernel(const float* __restrict__ pool,
                           const float* __restrict__ W1,
                           const float* __restrict__ b1,
                           const float* __restrict__ W2,
                           const float* __restrict__ b2,
                           float* __restrict__ out, float invN) {
  __shared__ float p[64], h[64];
  const int tid = threadIdx.x;
  if (tid < 64) p[tid] = pool[tid] * invN;
  __syncthreads();
  if (tid < 64) {
    float s = b1[tid];
    for (int k = 0; k < 64; k++) s = fmaf(p[k], W1[k * 64 + tid], s);
    h[tid] = fmaxf(s, 0.f);
  }
  __syncthreads();
  float s = b2[tid];
  for (int k = 0; k < 64; k++) s = fmaf(h[k], W2[k * 128 + tid], s);
  out[tid] = s;
}

extern "C" void kernel_launch(void* const* d_in, const int* in_sizes, int n_in,
                              void* d_out, int out_size, void* d_ws,
                              size_t ws_size, hipStream_t stream) {
  const int*   an  = (const int*)d_in[0];
  const int*   ei  = (const int*)d_in[3];
  const float* emb = (const float*)d_in[4];
  const float* Wl  = (const float*)d_in[5];
  const float* bl  = (const float*)d_in[6];
  const float* Wg  = (const float*)d_in[7];
  const float* bg  = (const float*)d_in[8];
  const float* W1  = (const float*)d_in[9];
  const float* b1  = (const float*)d_in[10];
  const float* W2  = (const float*)d_in[11];
  const float* b2  = (const float*)d_in[12];
  float* out = (float*)d_out;

  const int N = in_sizes[0];
  const int E = in_sizes[3] / 2;
  const int* row = ei;
  const int* col = ei + E;
  const int nbuck = (N + BROWS - 1) >> BSHIFT;

  const size_t NH = (size_t)N * H;
  char* ws = (char*)d_ws;
  ushort*   grA   = (ushort*)(ws);
  ushort*   grB   = (ushort*)(ws + NH * 2);
  uint32_t* glpkA = (uint32_t*)(ws + NH * 4);
  uint32_t* glpkB = (uint32_t*)(ws + NH * 4 + NH * 4);
  char* p = ws + NH * 4 + NH * 8;
  uint32_t* ebuf   = (uint32_t*)p; p += (size_t)E * 4;
  int*      cols   = (int*)p;      p += (size_t)E * 4;
  int*      offs   = (int*)p;      p += ((size_t)N + 1) * 4;
  int*      bcnt   = (int*)p;      p += 8192;
  int*      bstart = (int*)p;      p += 8196;
  int*      bcur   = (int*)p;      p += 8192;
  bf16x8*   wprep  = (bf16x8*)p;   p += 4608 * 16;
  float*    bgs    = (float*)p;    p += 192 * 4;
  float*    pool   = (float*)p;

  prep_kernel<<<18, 256, 0, stream>>>(Wl, Wg, bg, wprep, bgs);

  hipMemsetAsync(bcnt, 0, (size_t)nbuck * 4, stream);
  bucket_hist_kernel<<<1024, 256, 0, stream>>>(row, bcnt, E, nbuck);
  bucket_scan_kernel<<<1, 1024, 0, stream>>>(bcnt, bstart, bcur, offs, pool,
                                             nbuck, N, E);
  bucket_scatter_kernel<<<(E + SCHUNK - 1) / SCHUNK, 256, 0, stream>>>(
      row, col, bcur, ebuf, E, nbuck);
  csr_build_kernel<<<nbuck, 256, 0, stream>>>(ebuf, bstart, offs, cols, N);

  node_mm0_mfma<<<(N + 63) / 64, 256, 0, stream>>>(an, emb, wprep, bl, bgs,
                                                   grA, glpkA, N);

  const int aGrid = (N + 3) / 4;
  // agg(l0) + mm(l1): A -> B
  agg_mm_kernel<<<aGrid, 256, 0, stream>>>(grA, glpkA, offs, cols,
                                           wprep + 1536, bl + H, bgs + H,
                                           grB, glpkB, N);
  // agg(l1) + mm(l2): B -> A
  agg_mm_kernel<<<aGrid, 256, 0, stream>>>(grB, glpkB, offs, cols,
                                           wprep + 3072, bl + 2 * H,
                                           bgs + 2 * H, grA, glpkA, N);
  // agg(l2) + pool
  agg_pool_kernel<<<2048, 256, 0, stream>>>(grA, glpkA, offs, cols, pool, N);

  mlp_kernel<<<1, 128, 0, stream>>>(pool, W1, b1, W2, b2, out, 1.0f / (float)N);
}

// Round 12
// 394.134 us; speedup vs baseline: 1.4192x; 1.4192x over previous
//
#include <hip/hip_runtime.h>
#include <hip/hip_bf16.h>
#include <stdint.h>

// CrystalGraphEncoder on MI355X — round 12: disciplined revert/consolidation.
//  R11 post-mortem: agg loop 3x slower than R7's despite identical structure —
//  surrounding-code codegen perturbation (fused mm tail, shared __device__
//  helper, bf16-gr). R12 recombines only measured-best pieces:
//   - agg_kernel: VERBATIM R7 (54us/layer measured): f32 gr, __expf sigmoid,
//     4-deep, standalone kernel, writes x bf16.
//   - mm0/mmx separate MFMA kernels (R10-proven ~10us) w/ prepped bf16 weights.
//   - bucketed CSR chain verbatim R11 (~24us incl mm0).
//   - pool/mlp verbatim R7.
//
// ws: gr f32 | glpk u32 | x bf16 | ebuf | cols | offs | bcnt/bstart/bcur
//     | wprep | pool  (~73 MB)

#define H 64
#define BSHIFT 6
#define BROWS 64

typedef __attribute__((ext_vector_type(8))) short bf16x8;
typedef __attribute__((ext_vector_type(4))) float f32x4;

__device__ __forceinline__ ushort f2bf(float f) {  // RNE
  uint32_t u = __float_as_uint(f);
  u = (u + 0x7fffu + ((u >> 16) & 1u)) >> 16;
  return (ushort)u;
}
// pack: hi16 = bf16(lin), lo16 = bf16(gc)
__device__ __forceinline__ uint32_t pack_gl(float gc, float lin) {
  uint32_t ug = __float_as_uint(gc);
  ug = (ug + 0x7fffu + ((ug >> 16) & 1u)) >> 16;
  uint32_t ul = __float_as_uint(lin);
  ul = ((ul + 0x7fffu + ((ul >> 16) & 1u)) >> 16) << 16;
  return ul | ug;
}
__device__ __forceinline__ float unpack_gc(uint32_t p) {
  return __uint_as_float(p << 16);
}
__device__ __forceinline__ float unpack_lin(uint32_t p) {
  return __uint_as_float(p & 0xffff0000u);
}
__device__ __forceinline__ float sigmoidf_fast(float z) {
  return __builtin_amdgcn_rcpf(1.f + __expf(-z));
}

// ---------- prep: W -> bf16 frag-ready layout (no scaling) ----------
__global__ __launch_bounds__(256) void prep_kernel(
    const float* __restrict__ Wl, const float* __restrict__ Wg,
    bf16x8* __restrict__ wprep) {
  const int t = blockIdx.x * 256 + threadIdx.x;
  if (t >= 4608) return;
  const int l = t / 1536;
  const int rem = t - l * 1536;
  const int mat = rem >> 9;
  const int rem2 = rem & 511;
  const int nt = rem2 >> 7;
  const int ks = (rem2 >> 6) & 1;
  const int lane = rem2 & 63;
  const int kg = lane >> 4, l15 = lane & 15;
  const float* src;
  if (mat == 0)      src = Wl + (size_t)l * 4096;
  else if (mat == 1) src = Wg + (size_t)l * 8192;
  else               src = Wg + (size_t)l * 8192 + 4096;
  bf16x8 v;
#pragma unroll
  for (int j = 0; j < 8; j++)
    v[j] = (short)f2bf(src[(size_t)(ks * 32 + kg * 8 + j) * 64 + nt * 16 + l15]);
  wprep[t] = v;
}

// ---------- bucket hist / scan / scatter / csr (verbatim R11) ----------
__global__ __launch_bounds__(256) void bucket_hist_kernel(
    const int* __restrict__ row, int* __restrict__ bcnt, int E, int nbuck) {
  __shared__ int cnt[2048];
  const int tid = threadIdx.x;
  for (int b = tid; b < nbuck; b += 256) cnt[b] = 0;
  __syncthreads();
  for (int e = blockIdx.x * blockDim.x + tid; e < E; e += gridDim.x * blockDim.x)
    atomicAdd(&cnt[row[e] >> BSHIFT], 1);
  __syncthreads();
  for (int b = tid; b < nbuck; b += 256)
    if (cnt[b]) atomicAdd(&bcnt[b], cnt[b]);
}

__global__ __launch_bounds__(1024) void bucket_scan_kernel(
    const int* __restrict__ bcnt, int* __restrict__ bstart,
    int* __restrict__ bcur, int* __restrict__ offs, float* __restrict__ pool,
    int nbuck, int N, int E) {
  __shared__ int sh[1024];
  const int tid = threadIdx.x;
  if (tid < 64) pool[tid] = 0.f;
  const int i0 = 2 * tid, i1 = 2 * tid + 1;
  const int v0 = (i0 < nbuck) ? bcnt[i0] : 0;
  const int v1 = (i1 < nbuck) ? bcnt[i1] : 0;
  const int s = v0 + v1;
  sh[tid] = s;
  __syncthreads();
  for (int off = 1; off < 1024; off <<= 1) {
    const int v = (tid >= off) ? sh[tid - off] : 0;
    __syncthreads();
    sh[tid] += v;
    __syncthreads();
  }
  const int ex = sh[tid] - s;
  if (i0 < nbuck) { bstart[i0] = ex;      bcur[i0] = ex; }
  if (i1 < nbuck) { bstart[i1] = ex + v0; bcur[i1] = ex + v0; }
  if (tid == 0) { bstart[nbuck] = E; offs[N] = E; }
}

#define SCHUNK 4096
__global__ __launch_bounds__(256) void bucket_scatter_kernel(
    const int* __restrict__ row, const int* __restrict__ col,
    int* __restrict__ bcur, uint32_t* __restrict__ ebuf, int E, int nbuck) {
  __shared__ int cnt[2048], base[2048];
  const int tid = threadIdx.x;
  const int start = blockIdx.x * SCHUNK;
  const int end = min(start + SCHUNK, E);
  for (int b = tid; b < nbuck; b += 256) cnt[b] = 0;
  __syncthreads();
  for (int e = start + tid; e < end; e += 256)
    atomicAdd(&cnt[row[e] >> BSHIFT], 1);
  __syncthreads();
  for (int b = tid; b < nbuck; b += 256) {
    if (cnt[b]) base[b] = atomicAdd(&bcur[b], cnt[b]);
    cnt[b] = 0;
  }
  __syncthreads();
  for (int e = start + tid; e < end; e += 256) {
    const int r = row[e];
    const int b = r >> BSHIFT;
    const int pos = base[b] + atomicAdd(&cnt[b], 1);
    ebuf[pos] = ((uint32_t)(r & (BROWS - 1)) << 26) | (uint32_t)col[e];
  }
}

__global__ __launch_bounds__(256) void csr_build_kernel(
    const uint32_t* __restrict__ ebuf, const int* __restrict__ bstart,
    int* __restrict__ offs, int* __restrict__ cols, int N) {
  __shared__ int cnt[BROWS], sc[BROWS];
  const int tid = threadIdx.x;
  const int b = blockIdx.x;
  const int bs = bstart[b], be = bstart[b + 1];
  const int rowbase = b << BSHIFT;
  if (tid < BROWS) cnt[tid] = 0;
  __syncthreads();
  for (int e = bs + tid; e < be; e += 256)
    atomicAdd(&cnt[ebuf[e] >> 26], 1);
  __syncthreads();
  if (tid < BROWS) sc[tid] = cnt[tid];
  __syncthreads();
  for (int off = 1; off < BROWS; off <<= 1) {
    const int v = (tid >= off && tid < BROWS) ? sc[tid - off] : 0;
    __syncthreads();
    if (tid < BROWS) sc[tid] += v;
    __syncthreads();
  }
  if (tid < BROWS) {
    sc[tid] -= cnt[tid];
    cnt[tid] = 0;
    const int r = rowbase + tid;
    if (r < N) offs[r] = bs + sc[tid];
  }
  __syncthreads();
  for (int e = bs + tid; e < be; e += 256) {
    const uint32_t u = ebuf[e];
    const int rl = (int)(u >> 26);
    const int pos = sc[rl] + atomicAdd(&cnt[rl], 1);
    cols[bs + pos] = (int)(u & 0x3FFFFFFu);
  }
}

// ---------- mm0: embed -> layer-0 gr(f32)/glpk via MFMA ----------
__global__ __launch_bounds__(256) void node_mm0_mfma(
    const int* __restrict__ an, const float* __restrict__ emb,
    const bf16x8* __restrict__ wp, const float* __restrict__ bl,
    const float* __restrict__ bg, float* __restrict__ gr,
    uint32_t* __restrict__ glpk, int N) {
  const int tid = threadIdx.x;
  const int lane = tid & 63, wid = tid >> 6;
  const int l15 = lane & 15, kg = lane >> 4;

  bf16x8 bfrag[3][4][2];
#pragma unroll
  for (int mat = 0; mat < 3; mat++)
#pragma unroll
    for (int nt = 0; nt < 4; nt++)
#pragma unroll
      for (int ks = 0; ks < 2; ks++)
        bfrag[mat][nt][ks] = wp[(((mat * 4 + nt) * 2 + ks) << 6) + lane];

  const int mbase = blockIdx.x * 64 + wid * 16;
  const int arow_c = min(mbase + l15, N - 1);

  const int a = an[arow_c];
  const float* src = emb + (size_t)a * H + kg * 8;
  const float4 u0 = *(const float4*)(src);
  const float4 u1 = *(const float4*)(src + 4);
  const float4 u2 = *(const float4*)(src + 32);
  const float4 u3 = *(const float4*)(src + 36);
  bf16x8 afrag0, afrag1;
  afrag0[0] = (short)f2bf(u0.x); afrag0[1] = (short)f2bf(u0.y);
  afrag0[2] = (short)f2bf(u0.z); afrag0[3] = (short)f2bf(u0.w);
  afrag0[4] = (short)f2bf(u1.x); afrag0[5] = (short)f2bf(u1.y);
  afrag0[6] = (short)f2bf(u1.z); afrag0[7] = (short)f2bf(u1.w);
  afrag1[0] = (short)f2bf(u2.x); afrag1[1] = (short)f2bf(u2.y);
  afrag1[2] = (short)f2bf(u2.z); afrag1[3] = (short)f2bf(u2.w);
  afrag1[4] = (short)f2bf(u3.x); afrag1[5] = (short)f2bf(u3.y);
  afrag1[6] = (short)f2bf(u3.z); afrag1[7] = (short)f2bf(u3.w);

  f32x4 accL[4], accR[4], accC[4];
#pragma unroll
  for (int nt = 0; nt < 4; nt++) {
    const float blv = bl[nt * 16 + l15];
    const float bgv = bg[nt * 16 + l15];
    accL[nt] = (f32x4){blv, blv, blv, blv};
    accR[nt] = (f32x4){0.f, 0.f, 0.f, 0.f};
    accC[nt] = (f32x4){bgv, bgv, bgv, bgv};
  }
#pragma unroll
  for (int nt = 0; nt < 4; nt++) {
    accL[nt] = __builtin_amdgcn_mfma_f32_16x16x32_bf16(afrag0, bfrag[0][nt][0], accL[nt], 0, 0, 0);
    accL[nt] = __builtin_amdgcn_mfma_f32_16x16x32_bf16(afrag1, bfrag[0][nt][1], accL[nt], 0, 0, 0);
    accR[nt] = __builtin_amdgcn_mfma_f32_16x16x32_bf16(afrag0, bfrag[1][nt][0], accR[nt], 0, 0, 0);
    accR[nt] = __builtin_amdgcn_mfma_f32_16x16x32_bf16(afrag1, bfrag[1][nt][1], accR[nt], 0, 0, 0);
    accC[nt] = __builtin_amdgcn_mfma_f32_16x16x32_bf16(afrag0, bfrag[2][nt][0], accC[nt], 0, 0, 0);
    accC[nt] = __builtin_amdgcn_mfma_f32_16x16x32_bf16(afrag1, bfrag[2][nt][1], accC[nt], 0, 0, 0);
  }
#pragma unroll
  for (int nt = 0; nt < 4; nt++) {
#pragma unroll
    for (int r = 0; r < 4; r++) {
      const int atom = mbase + kg * 4 + r;
      if (atom < N) {
        const size_t o = (size_t)atom * H + nt * 16 + l15;
        gr[o] = accR[nt][r];
        glpk[o] = pack_gl(accC[nt][r], accL[nt][r]);
      }
    }
  }
}

// ---------- mmx: x(bf16) -> gr(f32)/glpk via MFMA (layers 1,2) ----------
__global__ __launch_bounds__(256) void node_mmx_mfma(
    const ushort* __restrict__ x, const bf16x8* __restrict__ wp,
    const float* __restrict__ bl, const float* __restrict__ bg,
    float* __restrict__ gr, uint32_t* __restrict__ glpk, int N) {
  const int tid = threadIdx.x;
  const int lane = tid & 63, wid = tid >> 6;
  const int l15 = lane & 15, kg = lane >> 4;

  bf16x8 bfrag[3][4][2];
#pragma unroll
  for (int mat = 0; mat < 3; mat++)
#pragma unroll
    for (int nt = 0; nt < 4; nt++)
#pragma unroll
      for (int ks = 0; ks < 2; ks++)
        bfrag[mat][nt][ks] = wp[(((mat * 4 + nt) * 2 + ks) << 6) + lane];

  const int mbase = blockIdx.x * 64 + wid * 16;
  const int arow_c = min(mbase + l15, N - 1);
  const ushort* src = x + (size_t)arow_c * H + kg * 8;
  const bf16x8 afrag0 = *(const bf16x8*)(src);
  const bf16x8 afrag1 = *(const bf16x8*)(src + 32);

  f32x4 accL[4], accR[4], accC[4];
#pragma unroll
  for (int nt = 0; nt < 4; nt++) {
    const float blv = bl[nt * 16 + l15];
    const float bgv = bg[nt * 16 + l15];
    accL[nt] = (f32x4){blv, blv, blv, blv};
    accR[nt] = (f32x4){0.f, 0.f, 0.f, 0.f};
    accC[nt] = (f32x4){bgv, bgv, bgv, bgv};
  }
#pragma unroll
  for (int nt = 0; nt < 4; nt++) {
    accL[nt] = __builtin_amdgcn_mfma_f32_16x16x32_bf16(afrag0, bfrag[0][nt][0], accL[nt], 0, 0, 0);
    accL[nt] = __builtin_amdgcn_mfma_f32_16x16x32_bf16(afrag1, bfrag[0][nt][1], accL[nt], 0, 0, 0);
    accR[nt] = __builtin_amdgcn_mfma_f32_16x16x32_bf16(afrag0, bfrag[1][nt][0], accR[nt], 0, 0, 0);
    accR[nt] = __builtin_amdgcn_mfma_f32_16x16x32_bf16(afrag1, bfrag[1][nt][1], accR[nt], 0, 0, 0);
    accC[nt] = __builtin_amdgcn_mfma_f32_16x16x32_bf16(afrag0, bfrag[2][nt][0], accC[nt], 0, 0, 0);
    accC[nt] = __builtin_amdgcn_mfma_f32_16x16x32_bf16(afrag1, bfrag[2][nt][1], accC[nt], 0, 0, 0);
  }
#pragma unroll
  for (int nt = 0; nt < 4; nt++) {
#pragma unroll
    for (int r = 0; r < 4; r++) {
      const int atom = mbase + kg * 4 + r;
      if (atom < N) {
        const size_t o = (size_t)atom * H + nt * 16 + l15;
        gr[o] = accR[nt][r];
        glpk[o] = pack_gl(accC[nt][r], accL[nt][r]);
      }
    }
  }
}

// ---------- aggregate + update: VERBATIM R7 (measured 54us/layer) ----------
__global__ __launch_bounds__(256) void agg_kernel(
    const float* __restrict__ gr, const uint32_t* __restrict__ glpk,
    const int* __restrict__ offs, const int* __restrict__ cols,
    ushort* __restrict__ x, int N) {
  const int lane = threadIdx.x & 63, w = threadIdx.x >> 6;
  for (int i = blockIdx.x * 4 + w; i < N; i += gridDim.x * 4) {
    const int s = offs[i], e = offs[i + 1];
    const float gri = gr[(size_t)i * H + lane];
    float acc = 0.f;
    for (int cb = s; cb < e; cb += 64) {
      const int nchunk = min(64, e - cb);
      const int myc = (lane < nchunk) ? cols[cb + lane] : 0;
      int j = 0;
      for (; j + 3 < nchunk; j += 4) {
        const int c0 = __shfl(myc, j + 0), c1 = __shfl(myc, j + 1);
        const int c2 = __shfl(myc, j + 2), c3 = __shfl(myc, j + 3);
        const uint32_t p0 = glpk[(size_t)c0 * H + lane];
        const uint32_t p1 = glpk[(size_t)c1 * H + lane];
        const uint32_t p2 = glpk[(size_t)c2 * H + lane];
        const uint32_t p3 = glpk[(size_t)c3 * H + lane];
        acc += unpack_lin(p0) * sigmoidf_fast(gri + unpack_gc(p0));
        acc += unpack_lin(p1) * sigmoidf_fast(gri + unpack_gc(p1));
        acc += unpack_lin(p2) * sigmoidf_fast(gri + unpack_gc(p2));
        acc += unpack_lin(p3) * sigmoidf_fast(gri + unpack_gc(p3));
      }
      for (; j < nchunk; j++) {
        const int c0 = __shfl(myc, j);
        const uint32_t p0 = glpk[(size_t)c0 * H + lane];
        acc += unpack_lin(p0) * sigmoidf_fast(gri + unpack_gc(p0));
      }
    }
    const float li = unpack_lin(glpk[(size_t)i * H + lane]);
    x[(size_t)i * H + lane] = f2bf(fmaxf(acc + li, 0.f));
  }
}

// ---------- mean pool (bf16 x), verbatim R7 ----------
__global__ void pool_kernel(const ushort* __restrict__ x,
                            float* __restrict__ pool, int N) {
  __shared__ float ps[4][64];
  const int tid = threadIdx.x, c = tid & 63, wid = tid >> 6;
  float s = 0.f;
  for (int i = blockIdx.x * 4 + wid; i < N; i += gridDim.x * 4)
    s += __uint_as_float(((uint32_t)x[(size_t)i * H + c]) << 16);
  ps[wid][c] = s;
  __syncthreads();
  if (tid < 64) {
    const float t = ps[0][tid] + ps[1][tid] + ps[2][tid] + ps[3][tid];
    atomicAdd(&pool[tid], t);
  }
}

// ---------- final MLP ----------
__global__ void mlp_kernel(const float* __restrict__ pool,
                           const float* __restrict__ W1,
                           const float* __restrict__ b1,
                           const float* __restrict__ W2,
                           const float* __restrict__ b2,
                           float* __restrict__ out, float invN) {
  __shared__ float p[64], h[64];
  const int tid = threadIdx.x;
  if (tid < 64) p[tid] = pool[tid] * invN;
  __syncthreads();
  if (tid < 64) {
    float s = b1[tid];
    for (int k = 0; k < 64; k++) s = fmaf(p[k], W1[k * 64 + tid], s);
    h[tid] = fmaxf(s, 0.f);
  }
  __syncthreads();
  float s = b2[tid];
  for (int k = 0; k < 64; k++) s = fmaf(h[k], W2[k * 128 + tid], s);
  out[tid] = s;
}

extern "C" void kernel_launch(void* const* d_in, const int* in_sizes, int n_in,
                              void* d_out, int out_size, void* d_ws,
                              size_t ws_size, hipStream_t stream) {
  const int*   an  = (const int*)d_in[0];
  const int*   ei  = (const int*)d_in[3];
  const float* emb = (const float*)d_in[4];
  const float* Wl  = (const float*)d_in[5];
  const float* bl  = (const float*)d_in[6];
  const float* Wg  = (const float*)d_in[7];
  const float* bg  = (const float*)d_in[8];
  const float* W1  = (const float*)d_in[9];
  const float* b1  = (const float*)d_in[10];
  const float* W2  = (const float*)d_in[11];
  const float* b2  = (const float*)d_in[12];
  float* out = (float*)d_out;

  const int N = in_sizes[0];
  const int E = in_sizes[3] / 2;
  const int* row = ei;
  const int* col = ei + E;
  const int nbuck = (N + BROWS - 1) >> BSHIFT;

  const size_t NH = (size_t)N * H;
  char* ws = (char*)d_ws;
  float*    gr   = (float*)(ws);                 // f32 [N][64]
  uint32_t* glpk = (uint32_t*)(ws + NH * 4);     // u32 [N][64]
  ushort*   x    = (ushort*)(ws + NH * 8);       // bf16 [N][64]
  char* p = ws + NH * 8 + NH * 2;
  uint32_t* ebuf   = (uint32_t*)p; p += (size_t)E * 4;
  int*      cols   = (int*)p;      p += (size_t)E * 4;
  int*      offs   = (int*)p;      p += ((size_t)N + 1) * 4;
  int*      bcnt   = (int*)p;      p += 8192;
  int*      bstart = (int*)p;      p += 8196;
  int*      bcur   = (int*)p;      p += 8192;
  bf16x8*   wprep  = (bf16x8*)p;   p += 4608 * 16;
  float*    pool   = (float*)p;
  // total ≈ 25.6 + 25.6 + 12.8 + 4 + 4 + 0.4 MB + ~100KB ≈ 72.5 MB

  prep_kernel<<<18, 256, 0, stream>>>(Wl, Wg, wprep);

  hipMemsetAsync(bcnt, 0, (size_t)nbuck * 4, stream);
  bucket_hist_kernel<<<1024, 256, 0, stream>>>(row, bcnt, E, nbuck);
  bucket_scan_kernel<<<1, 1024, 0, stream>>>(bcnt, bstart, bcur, offs, pool,
                                             nbuck, N, E);
  bucket_scatter_kernel<<<(E + SCHUNK - 1) / SCHUNK, 256, 0, stream>>>(
      row, col, bcur, ebuf, E, nbuck);
  csr_build_kernel<<<nbuck, 256, 0, stream>>>(ebuf, bstart, offs, cols, N);

  const int mmGrid = (N + 63) / 64;
  const int aggGrid = (N + 3) / 4;

  node_mm0_mfma<<<mmGrid, 256, 0, stream>>>(an, emb, wprep, bl, bg, gr, glpk, N);
  for (int l = 0; l < 3; l++) {
    agg_kernel<<<aggGrid, 256, 0, stream>>>(gr, glpk, offs, cols, x, N);
    if (l < 2)
      node_mmx_mfma<<<mmGrid, 256, 0, stream>>>(
          x, wprep + (size_t)(l + 1) * 1536, bl + (size_t)(l + 1) * H,
          bg + (size_t)(l + 1) * H, gr, glpk, N);
  }

  pool_kernel<<<1024, 256, 0, stream>>>(x, pool, N);
  mlp_kernel<<<1, 128, 0, stream>>>(pool, W1, b1, W2, b2, out, 1.0f / (float)N);
}

// Round 13
// 387.665 us; speedup vs baseline: 1.4429x; 1.0167x over previous
//
#include <hip/hip_runtime.h>
#include <hip/hip_bf16.h>
#include <stdint.h>

// CrystalGraphEncoder on MI355X — round 13:
//  R12 post-mortem: agg restored to 54us (codegen-perturbation confirmed).
//  ~230us remains outside agg; prime suspect = mm kernels (~180 VGPR from 24
//  live B-frags + 12 accs -> 2 waves/SIMD). R13 changes ONLY mm0/mmx:
//  per-matrix loop (lin -> keep 16 f32; gc -> pack+store; gr -> store),
//  ~8 B-frag regs in flight. bcnt memset folded into prep (one less dispatch).
//  agg / CSR chain / pool / mlp BYTE-IDENTICAL to R12.
//
// ws: gr f32 | glpk u32 | x bf16 | ebuf | cols | offs | bcnt/bstart/bcur
//     | wprep | pool  (~73 MB)

#define H 64
#define BSHIFT 6
#define BROWS 64

typedef __attribute__((ext_vector_type(8))) short bf16x8;
typedef __attribute__((ext_vector_type(4))) float f32x4;

__device__ __forceinline__ ushort f2bf(float f) {  // RNE
  uint32_t u = __float_as_uint(f);
  u = (u + 0x7fffu + ((u >> 16) & 1u)) >> 16;
  return (ushort)u;
}
// pack: hi16 = bf16(lin), lo16 = bf16(gc)
__device__ __forceinline__ uint32_t pack_gl(float gc, float lin) {
  uint32_t ug = __float_as_uint(gc);
  ug = (ug + 0x7fffu + ((ug >> 16) & 1u)) >> 16;
  uint32_t ul = __float_as_uint(lin);
  ul = ((ul + 0x7fffu + ((ul >> 16) & 1u)) >> 16) << 16;
  return ul | ug;
}
__device__ __forceinline__ float unpack_gc(uint32_t p) {
  return __uint_as_float(p << 16);
}
__device__ __forceinline__ float unpack_lin(uint32_t p) {
  return __uint_as_float(p & 0xffff0000u);
}
__device__ __forceinline__ float sigmoidf_fast(float z) {
  return __builtin_amdgcn_rcpf(1.f + __expf(-z));
}

// ---------- prep: W -> bf16 frag-ready layout; also zeroes bcnt ----------
__global__ __launch_bounds__(256) void prep_kernel(
    const float* __restrict__ Wl, const float* __restrict__ Wg,
    bf16x8* __restrict__ wprep, int* __restrict__ bcnt, int nbuck) {
  const int t = blockIdx.x * 256 + threadIdx.x;
  if (t < nbuck) bcnt[t] = 0;
  if (t >= 4608) return;
  const int l = t / 1536;
  const int rem = t - l * 1536;
  const int mat = rem >> 9;
  const int rem2 = rem & 511;
  const int nt = rem2 >> 7;
  const int ks = (rem2 >> 6) & 1;
  const int lane = rem2 & 63;
  const int kg = lane >> 4, l15 = lane & 15;
  const float* src;
  if (mat == 0)      src = Wl + (size_t)l * 4096;
  else if (mat == 1) src = Wg + (size_t)l * 8192;
  else               src = Wg + (size_t)l * 8192 + 4096;
  bf16x8 v;
#pragma unroll
  for (int j = 0; j < 8; j++)
    v[j] = (short)f2bf(src[(size_t)(ks * 32 + kg * 8 + j) * 64 + nt * 16 + l15]);
  wprep[t] = v;
}

// ---------- bucket hist / scan / scatter / csr (verbatim R12) ----------
__global__ __launch_bounds__(256) void bucket_hist_kernel(
    const int* __restrict__ row, int* __restrict__ bcnt, int E, int nbuck) {
  __shared__ int cnt[2048];
  const int tid = threadIdx.x;
  for (int b = tid; b < nbuck; b += 256) cnt[b] = 0;
  __syncthreads();
  for (int e = blockIdx.x * blockDim.x + tid; e < E; e += gridDim.x * blockDim.x)
    atomicAdd(&cnt[row[e] >> BSHIFT], 1);
  __syncthreads();
  for (int b = tid; b < nbuck; b += 256)
    if (cnt[b]) atomicAdd(&bcnt[b], cnt[b]);
}

__global__ __launch_bounds__(1024) void bucket_scan_kernel(
    const int* __restrict__ bcnt, int* __restrict__ bstart,
    int* __restrict__ bcur, int* __restrict__ offs, float* __restrict__ pool,
    int nbuck, int N, int E) {
  __shared__ int sh[1024];
  const int tid = threadIdx.x;
  if (tid < 64) pool[tid] = 0.f;
  const int i0 = 2 * tid, i1 = 2 * tid + 1;
  const int v0 = (i0 < nbuck) ? bcnt[i0] : 0;
  const int v1 = (i1 < nbuck) ? bcnt[i1] : 0;
  const int s = v0 + v1;
  sh[tid] = s;
  __syncthreads();
  for (int off = 1; off < 1024; off <<= 1) {
    const int v = (tid >= off) ? sh[tid - off] : 0;
    __syncthreads();
    sh[tid] += v;
    __syncthreads();
  }
  const int ex = sh[tid] - s;
  if (i0 < nbuck) { bstart[i0] = ex;      bcur[i0] = ex; }
  if (i1 < nbuck) { bstart[i1] = ex + v0; bcur[i1] = ex + v0; }
  if (tid == 0) { bstart[nbuck] = E; offs[N] = E; }
}

#define SCHUNK 4096
__global__ __launch_bounds__(256) void bucket_scatter_kernel(
    const int* __restrict__ row, const int* __restrict__ col,
    int* __restrict__ bcur, uint32_t* __restrict__ ebuf, int E, int nbuck) {
  __shared__ int cnt[2048], base[2048];
  const int tid = threadIdx.x;
  const int start = blockIdx.x * SCHUNK;
  const int end = min(start + SCHUNK, E);
  for (int b = tid; b < nbuck; b += 256) cnt[b] = 0;
  __syncthreads();
  for (int e = start + tid; e < end; e += 256)
    atomicAdd(&cnt[row[e] >> BSHIFT], 1);
  __syncthreads();
  for (int b = tid; b < nbuck; b += 256) {
    if (cnt[b]) base[b] = atomicAdd(&bcur[b], cnt[b]);
    cnt[b] = 0;
  }
  __syncthreads();
  for (int e = start + tid; e < end; e += 256) {
    const int r = row[e];
    const int b = r >> BSHIFT;
    const int pos = base[b] + atomicAdd(&cnt[b], 1);
    ebuf[pos] = ((uint32_t)(r & (BROWS - 1)) << 26) | (uint32_t)col[e];
  }
}

__global__ __launch_bounds__(256) void csr_build_kernel(
    const uint32_t* __restrict__ ebuf, const int* __restrict__ bstart,
    int* __restrict__ offs, int* __restrict__ cols, int N) {
  __shared__ int cnt[BROWS], sc[BROWS];
  const int tid = threadIdx.x;
  const int b = blockIdx.x;
  const int bs = bstart[b], be = bstart[b + 1];
  const int rowbase = b << BSHIFT;
  if (tid < BROWS) cnt[tid] = 0;
  __syncthreads();
  for (int e = bs + tid; e < be; e += 256)
    atomicAdd(&cnt[ebuf[e] >> 26], 1);
  __syncthreads();
  if (tid < BROWS) sc[tid] = cnt[tid];
  __syncthreads();
  for (int off = 1; off < BROWS; off <<= 1) {
    const int v = (tid >= off && tid < BROWS) ? sc[tid - off] : 0;
    __syncthreads();
    if (tid < BROWS) sc[tid] += v;
    __syncthreads();
  }
  if (tid < BROWS) {
    sc[tid] -= cnt[tid];
    cnt[tid] = 0;
    const int r = rowbase + tid;
    if (r < N) offs[r] = bs + sc[tid];
  }
  __syncthreads();
  for (int e = bs + tid; e < be; e += 256) {
    const uint32_t u = ebuf[e];
    const int rl = (int)(u >> 26);
    const int pos = sc[rl] + atomicAdd(&cnt[rl], 1);
    cols[bs + pos] = (int)(u & 0x3FFFFFFu);
  }
}

// ---------- mm0: embed -> layer-0 gr(f32)/glpk; per-mat loop (low VGPR) ----------
__global__ __launch_bounds__(256) void node_mm0_mfma(
    const int* __restrict__ an, const float* __restrict__ emb,
    const bf16x8* __restrict__ wp, const float* __restrict__ bl,
    const float* __restrict__ bg, float* __restrict__ gr,
    uint32_t* __restrict__ glpk, int N) {
  const int tid = threadIdx.x;
  const int lane = tid & 63, wid = tid >> 6;
  const int l15 = lane & 15, kg = lane >> 4;
  const int mbase = blockIdx.x * 64 + wid * 16;
  const int arow_c = min(mbase + l15, N - 1);

  const int a = an[arow_c];
  const float* src = emb + (size_t)a * H + kg * 8;
  const float4 u0 = *(const float4*)(src);
  const float4 u1 = *(const float4*)(src + 4);
  const float4 u2 = *(const float4*)(src + 32);
  const float4 u3 = *(const float4*)(src + 36);
  bf16x8 a0, a1;
  a0[0] = (short)f2bf(u0.x); a0[1] = (short)f2bf(u0.y);
  a0[2] = (short)f2bf(u0.z); a0[3] = (short)f2bf(u0.w);
  a0[4] = (short)f2bf(u1.x); a0[5] = (short)f2bf(u1.y);
  a0[6] = (short)f2bf(u1.z); a0[7] = (short)f2bf(u1.w);
  a1[0] = (short)f2bf(u2.x); a1[1] = (short)f2bf(u2.y);
  a1[2] = (short)f2bf(u2.z); a1[3] = (short)f2bf(u2.w);
  a1[4] = (short)f2bf(u3.x); a1[5] = (short)f2bf(u3.y);
  a1[6] = (short)f2bf(u3.z); a1[7] = (short)f2bf(u3.w);

  // mat 0: lin — keep results
  float linv[4][4];
#pragma unroll
  for (int nt = 0; nt < 4; nt++) {
    const float blv = bl[nt * 16 + l15];
    f32x4 acc = (f32x4){blv, blv, blv, blv};
    acc = __builtin_amdgcn_mfma_f32_16x16x32_bf16(a0, wp[(((0 * 4 + nt) * 2 + 0) << 6) + lane], acc, 0, 0, 0);
    acc = __builtin_amdgcn_mfma_f32_16x16x32_bf16(a1, wp[(((0 * 4 + nt) * 2 + 1) << 6) + lane], acc, 0, 0, 0);
#pragma unroll
    for (int r = 0; r < 4; r++) linv[nt][r] = acc[r];
  }
  // mat 2: gc -> pack with lin, store glpk
#pragma unroll
  for (int nt = 0; nt < 4; nt++) {
    const float bgv = bg[nt * 16 + l15];
    f32x4 acc = (f32x4){bgv, bgv, bgv, bgv};
    acc = __builtin_amdgcn_mfma_f32_16x16x32_bf16(a0, wp[(((2 * 4 + nt) * 2 + 0) << 6) + lane], acc, 0, 0, 0);
    acc = __builtin_amdgcn_mfma_f32_16x16x32_bf16(a1, wp[(((2 * 4 + nt) * 2 + 1) << 6) + lane], acc, 0, 0, 0);
#pragma unroll
    for (int r = 0; r < 4; r++) {
      const int atom = mbase + kg * 4 + r;
      if (atom < N)
        glpk[(size_t)atom * H + nt * 16 + l15] = pack_gl(acc[r], linv[nt][r]);
    }
  }
  // mat 1: gr
#pragma unroll
  for (int nt = 0; nt < 4; nt++) {
    f32x4 acc = (f32x4){0.f, 0.f, 0.f, 0.f};
    acc = __builtin_amdgcn_mfma_f32_16x16x32_bf16(a0, wp[(((1 * 4 + nt) * 2 + 0) << 6) + lane], acc, 0, 0, 0);
    acc = __builtin_amdgcn_mfma_f32_16x16x32_bf16(a1, wp[(((1 * 4 + nt) * 2 + 1) << 6) + lane], acc, 0, 0, 0);
#pragma unroll
    for (int r = 0; r < 4; r++) {
      const int atom = mbase + kg * 4 + r;
      if (atom < N) gr[(size_t)atom * H + nt * 16 + l15] = acc[r];
    }
  }
}

// ---------- mmx: x(bf16) -> gr(f32)/glpk; per-mat loop (low VGPR) ----------
__global__ __launch_bounds__(256) void node_mmx_mfma(
    const ushort* __restrict__ x, const bf16x8* __restrict__ wp,
    const float* __restrict__ bl, const float* __restrict__ bg,
    float* __restrict__ gr, uint32_t* __restrict__ glpk, int N) {
  const int tid = threadIdx.x;
  const int lane = tid & 63, wid = tid >> 6;
  const int l15 = lane & 15, kg = lane >> 4;
  const int mbase = blockIdx.x * 64 + wid * 16;
  const int arow_c = min(mbase + l15, N - 1);
  const ushort* src = x + (size_t)arow_c * H + kg * 8;
  const bf16x8 a0 = *(const bf16x8*)(src);
  const bf16x8 a1 = *(const bf16x8*)(src + 32);

  float linv[4][4];
#pragma unroll
  for (int nt = 0; nt < 4; nt++) {
    const float blv = bl[nt * 16 + l15];
    f32x4 acc = (f32x4){blv, blv, blv, blv};
    acc = __builtin_amdgcn_mfma_f32_16x16x32_bf16(a0, wp[(((0 * 4 + nt) * 2 + 0) << 6) + lane], acc, 0, 0, 0);
    acc = __builtin_amdgcn_mfma_f32_16x16x32_bf16(a1, wp[(((0 * 4 + nt) * 2 + 1) << 6) + lane], acc, 0, 0, 0);
#pragma unroll
    for (int r = 0; r < 4; r++) linv[nt][r] = acc[r];
  }
#pragma unroll
  for (int nt = 0; nt < 4; nt++) {
    const float bgv = bg[nt * 16 + l15];
    f32x4 acc = (f32x4){bgv, bgv, bgv, bgv};
    acc = __builtin_amdgcn_mfma_f32_16x16x32_bf16(a0, wp[(((2 * 4 + nt) * 2 + 0) << 6) + lane], acc, 0, 0, 0);
    acc = __builtin_amdgcn_mfma_f32_16x16x32_bf16(a1, wp[(((2 * 4 + nt) * 2 + 1) << 6) + lane], acc, 0, 0, 0);
#pragma unroll
    for (int r = 0; r < 4; r++) {
      const int atom = mbase + kg * 4 + r;
      if (atom < N)
        glpk[(size_t)atom * H + nt * 16 + l15] = pack_gl(acc[r], linv[nt][r]);
    }
  }
#pragma unroll
  for (int nt = 0; nt < 4; nt++) {
    f32x4 acc = (f32x4){0.f, 0.f, 0.f, 0.f};
    acc = __builtin_amdgcn_mfma_f32_16x16x32_bf16(a0, wp[(((1 * 4 + nt) * 2 + 0) << 6) + lane], acc, 0, 0, 0);
    acc = __builtin_amdgcn_mfma_f32_16x16x32_bf16(a1, wp[(((1 * 4 + nt) * 2 + 1) << 6) + lane], acc, 0, 0, 0);
#pragma unroll
    for (int r = 0; r < 4; r++) {
      const int atom = mbase + kg * 4 + r;
      if (atom < N) gr[(size_t)atom * H + nt * 16 + l15] = acc[r];
    }
  }
}

// ---------- aggregate + update: VERBATIM R12 (measured 54us/layer) ----------
__global__ __launch_bounds__(256) void agg_kernel(
    const float* __restrict__ gr, const uint32_t* __restrict__ glpk,
    const int* __restrict__ offs, const int* __restrict__ cols,
    ushort* __restrict__ x, int N) {
  const int lane = threadIdx.x & 63, w = threadIdx.x >> 6;
  for (int i = blockIdx.x * 4 + w; i < N; i += gridDim.x * 4) {
    const int s = offs[i], e = offs[i + 1];
    const float gri = gr[(size_t)i * H + lane];
    float acc = 0.f;
    for (int cb = s; cb < e; cb += 64) {
      const int nchunk = min(64, e - cb);
      const int myc = (lane < nchunk) ? cols[cb + lane] : 0;
      int j = 0;
      for (; j + 3 < nchunk; j += 4) {
        const int c0 = __shfl(myc, j + 0), c1 = __shfl(myc, j + 1);
        const int c2 = __shfl(myc, j + 2), c3 = __shfl(myc, j + 3);
        const uint32_t p0 = glpk[(size_t)c0 * H + lane];
        const uint32_t p1 = glpk[(size_t)c1 * H + lane];
        const uint32_t p2 = glpk[(size_t)c2 * H + lane];
        const uint32_t p3 = glpk[(size_t)c3 * H + lane];
        acc += unpack_lin(p0) * sigmoidf_fast(gri + unpack_gc(p0));
        acc += unpack_lin(p1) * sigmoidf_fast(gri + unpack_gc(p1));
        acc += unpack_lin(p2) * sigmoidf_fast(gri + unpack_gc(p2));
        acc += unpack_lin(p3) * sigmoidf_fast(gri + unpack_gc(p3));
      }
      for (; j < nchunk; j++) {
        const int c0 = __shfl(myc, j);
        const uint32_t p0 = glpk[(size_t)c0 * H + lane];
        acc += unpack_lin(p0) * sigmoidf_fast(gri + unpack_gc(p0));
      }
    }
    const float li = unpack_lin(glpk[(size_t)i * H + lane]);
    x[(size_t)i * H + lane] = f2bf(fmaxf(acc + li, 0.f));
  }
}

// ---------- mean pool (bf16 x), verbatim R12 ----------
__global__ void pool_kernel(const ushort* __restrict__ x,
                            float* __restrict__ pool, int N) {
  __shared__ float ps[4][64];
  const int tid = threadIdx.x, c = tid & 63, wid = tid >> 6;
  float s = 0.f;
  for (int i = blockIdx.x * 4 + wid; i < N; i += gridDim.x * 4)
    s += __uint_as_float(((uint32_t)x[(size_t)i * H + c]) << 16);
  ps[wid][c] = s;
  __syncthreads();
  if (tid < 64) {
    const float t = ps[0][tid] + ps[1][tid] + ps[2][tid] + ps[3][tid];
    atomicAdd(&pool[tid], t);
  }
}

// ---------- final MLP ----------
__global__ void mlp_kernel(const float* __restrict__ pool,
                           const float* __restrict__ W1,
                           const float* __restrict__ b1,
                           const float* __restrict__ W2,
                           const float* __restrict__ b2,
                           float* __restrict__ out, float invN) {
  __shared__ float p[64], h[64];
  const int tid = threadIdx.x;
  if (tid < 64) p[tid] = pool[tid] * invN;
  __syncthreads();
  if (tid < 64) {
    float s = b1[tid];
    for (int k = 0; k < 64; k++) s = fmaf(p[k], W1[k * 64 + tid], s);
    h[tid] = fmaxf(s, 0.f);
  }
  __syncthreads();
  float s = b2[tid];
  for (int k = 0; k < 64; k++) s = fmaf(h[k], W2[k * 128 + tid], s);
  out[tid] = s;
}

extern "C" void kernel_launch(void* const* d_in, const int* in_sizes, int n_in,
                              void* d_out, int out_size, void* d_ws,
                              size_t ws_size, hipStream_t stream) {
  const int*   an  = (const int*)d_in[0];
  const int*   ei  = (const int*)d_in[3];
  const float* emb = (const float*)d_in[4];
  const float* Wl  = (const float*)d_in[5];
  const float* bl  = (const float*)d_in[6];
  const float* Wg  = (const float*)d_in[7];
  const float* bg  = (const float*)d_in[8];
  const float* W1  = (const float*)d_in[9];
  const float* b1  = (const float*)d_in[10];
  const float* W2  = (const float*)d_in[11];
  const float* b2  = (const float*)d_in[12];
  float* out = (float*)d_out;

  const int N = in_sizes[0];
  const int E = in_sizes[3] / 2;
  const int* row = ei;
  const int* col = ei + E;
  const int nbuck = (N + BROWS - 1) >> BSHIFT;

  const size_t NH = (size_t)N * H;
  char* ws = (char*)d_ws;
  float*    gr   = (float*)(ws);                 // f32 [N][64]
  uint32_t* glpk = (uint32_t*)(ws + NH * 4);     // u32 [N][64]
  ushort*   x    = (ushort*)(ws + NH * 8);       // bf16 [N][64]
  char* p = ws + NH * 8 + NH * 2;
  uint32_t* ebuf   = (uint32_t*)p; p += (size_t)E * 4;
  int*      cols   = (int*)p;      p += (size_t)E * 4;
  int*      offs   = (int*)p;      p += ((size_t)N + 1) * 4;
  int*      bcnt   = (int*)p;      p += 8192;
  int*      bstart = (int*)p;      p += 8196;
  int*      bcur   = (int*)p;      p += 8192;
  bf16x8*   wprep  = (bf16x8*)p;   p += 4608 * 16;
  float*    pool   = (float*)p;
  // total ≈ 25.6 + 25.6 + 12.8 + 4 + 4 + 0.4 MB + ~100KB ≈ 72.5 MB

  prep_kernel<<<18, 256, 0, stream>>>(Wl, Wg, wprep, bcnt, nbuck);

  bucket_hist_kernel<<<1024, 256, 0, stream>>>(row, bcnt, E, nbuck);
  bucket_scan_kernel<<<1, 1024, 0, stream>>>(bcnt, bstart, bcur, offs, pool,
                                             nbuck, N, E);
  bucket_scatter_kernel<<<(E + SCHUNK - 1) / SCHUNK, 256, 0, stream>>>(
      row, col, bcur, ebuf, E, nbuck);
  csr_build_kernel<<<nbuck, 256, 0, stream>>>(ebuf, bstart, offs, cols, N);

  const int mmGrid = (N + 63) / 64;
  const int aggGrid = (N + 3) / 4;

  node_mm0_mfma<<<mmGrid, 256, 0, stream>>>(an, emb, wprep, bl, bg, gr, glpk, N);
  for (int l = 0; l < 3; l++) {
    agg_kernel<<<aggGrid, 256, 0, stream>>>(gr, glpk, offs, cols, x, N);
    if (l < 2)
      node_mmx_mfma<<<mmGrid, 256, 0, stream>>>(
          x, wprep + (size_t)(l + 1) * 1536, bl + (size_t)(l + 1) * H,
          bg + (size_t)(l + 1) * H, gr, glpk, N);
  }

  pool_kernel<<<1024, 256, 0, stream>>>(x, pool, N);
  mlp_kernel<<<1, 128, 0, stream>>>(pool, W1, b1, W2, b2, out, 1.0f / (float)N);
}

// Round 15
// 378.670 us; speedup vs baseline: 1.4771x; 1.0238x over previous
//
#include <hip/hip_runtime.h>
#include <hip/hip_bf16.h>
#include <stdint.h>

// CrystalGraphEncoder on MI355X — round 14 (resubmit after container failure):
//  R13 post-mortem: agg stable 53.5us x3 (FETCH 137MB); mm ~45us each; the
//  big lever left is agg gather traffic. R14: payload -> fp8 pair
//  (e4m3 gc, e4m3 lin) in ONE u16/channel via HW cvt_pk_fp8/cvt_f32_fp8:
//   - per-edge gather = one 128B line (was 256B / two lines)
//   - glpk array 25.6 -> 12.8MB (much closer to L2-resident)
//   - mm kernels write 12.8MB less each
//  Precision: weight (systematic) error dominates absmax; fp8 activation noise
//  is zero-mean per atom and pooling averages ~300x. Everything else verbatim R13.
//
// ws: gr f32 | glpk8 u16 | x bf16 | ebuf | cols | offs | bcnt/bstart/bcur
//     | wprep | pool  (~60 MB)

#define H 64
#define BSHIFT 6
#define BROWS 64

typedef __attribute__((ext_vector_type(8))) short bf16x8;
typedef __attribute__((ext_vector_type(4))) float f32x4;

__device__ __forceinline__ ushort f2bf(float f) {  // RNE
  uint32_t u = __float_as_uint(f);
  u = (u + 0x7fffu + ((u >> 16) & 1u)) >> 16;
  return (ushort)u;
}
// pack: byte0 = fp8(gc), byte1 = fp8(lin)   (OCP e4m3fn, HW convert)
__device__ __forceinline__ ushort pack_gl8(float gc, float lin) {
  return (ushort)(__builtin_amdgcn_cvt_pk_fp8_f32(gc, lin, 0, false) & 0xffff);
}
__device__ __forceinline__ float unpack_gc8(ushort p) {
  return __builtin_amdgcn_cvt_f32_fp8((int)p, 0);
}
__device__ __forceinline__ float unpack_lin8(ushort p) {
  return __builtin_amdgcn_cvt_f32_fp8((int)p, 1);
}
__device__ __forceinline__ float sigmoidf_fast(float z) {
  return __builtin_amdgcn_rcpf(1.f + __expf(-z));
}

// ---------- prep: W -> bf16 frag-ready layout; also zeroes bcnt ----------
__global__ __launch_bounds__(256) void prep_kernel(
    const float* __restrict__ Wl, const float* __restrict__ Wg,
    bf16x8* __restrict__ wprep, int* __restrict__ bcnt, int nbuck) {
  const int t = blockIdx.x * 256 + threadIdx.x;
  if (t < nbuck) bcnt[t] = 0;
  if (t >= 4608) return;
  const int l = t / 1536;
  const int rem = t - l * 1536;
  const int mat = rem >> 9;
  const int rem2 = rem & 511;
  const int nt = rem2 >> 7;
  const int ks = (rem2 >> 6) & 1;
  const int lane = rem2 & 63;
  const int kg = lane >> 4, l15 = lane & 15;
  const float* src;
  if (mat == 0)      src = Wl + (size_t)l * 4096;
  else if (mat == 1) src = Wg + (size_t)l * 8192;
  else               src = Wg + (size_t)l * 8192 + 4096;
  bf16x8 v;
#pragma unroll
  for (int j = 0; j < 8; j++)
    v[j] = (short)f2bf(src[(size_t)(ks * 32 + kg * 8 + j) * 64 + nt * 16 + l15]);
  wprep[t] = v;
}

// ---------- bucket hist / scan / scatter / csr (verbatim R13) ----------
__global__ __launch_bounds__(256) void bucket_hist_kernel(
    const int* __restrict__ row, int* __restrict__ bcnt, int E, int nbuck) {
  __shared__ int cnt[2048];
  const int tid = threadIdx.x;
  for (int b = tid; b < nbuck; b += 256) cnt[b] = 0;
  __syncthreads();
  for (int e = blockIdx.x * blockDim.x + tid; e < E; e += gridDim.x * blockDim.x)
    atomicAdd(&cnt[row[e] >> BSHIFT], 1);
  __syncthreads();
  for (int b = tid; b < nbuck; b += 256)
    if (cnt[b]) atomicAdd(&bcnt[b], cnt[b]);
}

__global__ __launch_bounds__(1024) void bucket_scan_kernel(
    const int* __restrict__ bcnt, int* __restrict__ bstart,
    int* __restrict__ bcur, int* __restrict__ offs, float* __restrict__ pool,
    int nbuck, int N, int E) {
  __shared__ int sh[1024];
  const int tid = threadIdx.x;
  if (tid < 64) pool[tid] = 0.f;
  const int i0 = 2 * tid, i1 = 2 * tid + 1;
  const int v0 = (i0 < nbuck) ? bcnt[i0] : 0;
  const int v1 = (i1 < nbuck) ? bcnt[i1] : 0;
  const int s = v0 + v1;
  sh[tid] = s;
  __syncthreads();
  for (int off = 1; off < 1024; off <<= 1) {
    const int v = (tid >= off) ? sh[tid - off] : 0;
    __syncthreads();
    sh[tid] += v;
    __syncthreads();
  }
  const int ex = sh[tid] - s;
  if (i0 < nbuck) { bstart[i0] = ex;      bcur[i0] = ex; }
  if (i1 < nbuck) { bstart[i1] = ex + v0; bcur[i1] = ex + v0; }
  if (tid == 0) { bstart[nbuck] = E; offs[N] = E; }
}

#define SCHUNK 4096
__global__ __launch_bounds__(256) void bucket_scatter_kernel(
    const int* __restrict__ row, const int* __restrict__ col,
    int* __restrict__ bcur, uint32_t* __restrict__ ebuf, int E, int nbuck) {
  __shared__ int cnt[2048], base[2048];
  const int tid = threadIdx.x;
  const int start = blockIdx.x * SCHUNK;
  const int end = min(start + SCHUNK, E);
  for (int b = tid; b < nbuck; b += 256) cnt[b] = 0;
  __syncthreads();
  for (int e = start + tid; e < end; e += 256)
    atomicAdd(&cnt[row[e] >> BSHIFT], 1);
  __syncthreads();
  for (int b = tid; b < nbuck; b += 256) {
    if (cnt[b]) base[b] = atomicAdd(&bcur[b], cnt[b]);
    cnt[b] = 0;
  }
  __syncthreads();
  for (int e = start + tid; e < end; e += 256) {
    const int r = row[e];
    const int b = r >> BSHIFT;
    const int pos = base[b] + atomicAdd(&cnt[b], 1);
    ebuf[pos] = ((uint32_t)(r & (BROWS - 1)) << 26) | (uint32_t)col[e];
  }
}

__global__ __launch_bounds__(256) void csr_build_kernel(
    const uint32_t* __restrict__ ebuf, const int* __restrict__ bstart,
    int* __restrict__ offs, int* __restrict__ cols, int N) {
  __shared__ int cnt[BROWS], sc[BROWS];
  const int tid = threadIdx.x;
  const int b = blockIdx.x;
  const int bs = bstart[b], be = bstart[b + 1];
  const int rowbase = b << BSHIFT;
  if (tid < BROWS) cnt[tid] = 0;
  __syncthreads();
  for (int e = bs + tid; e < be; e += 256)
    atomicAdd(&cnt[ebuf[e] >> 26], 1);
  __syncthreads();
  if (tid < BROWS) sc[tid] = cnt[tid];
  __syncthreads();
  for (int off = 1; off < BROWS; off <<= 1) {
    const int v = (tid >= off && tid < BROWS) ? sc[tid - off] : 0;
    __syncthreads();
    if (tid < BROWS) sc[tid] += v;
    __syncthreads();
  }
  if (tid < BROWS) {
    sc[tid] -= cnt[tid];
    cnt[tid] = 0;
    const int r = rowbase + tid;
    if (r < N) offs[r] = bs + sc[tid];
  }
  __syncthreads();
  for (int e = bs + tid; e < be; e += 256) {
    const uint32_t u = ebuf[e];
    const int rl = (int)(u >> 26);
    const int pos = sc[rl] + atomicAdd(&cnt[rl], 1);
    cols[bs + pos] = (int)(u & 0x3FFFFFFu);
  }
}

// ---------- mm0: embed -> layer-0 gr(f32)/glpk8; per-mat loop ----------
__global__ __launch_bounds__(256) void node_mm0_mfma(
    const int* __restrict__ an, const float* __restrict__ emb,
    const bf16x8* __restrict__ wp, const float* __restrict__ bl,
    const float* __restrict__ bg, float* __restrict__ gr,
    ushort* __restrict__ glpk8, int N) {
  const int tid = threadIdx.x;
  const int lane = tid & 63, wid = tid >> 6;
  const int l15 = lane & 15, kg = lane >> 4;
  const int mbase = blockIdx.x * 64 + wid * 16;
  const int arow_c = min(mbase + l15, N - 1);

  const int a = an[arow_c];
  const float* src = emb + (size_t)a * H + kg * 8;
  const float4 u0 = *(const float4*)(src);
  const float4 u1 = *(const float4*)(src + 4);
  const float4 u2 = *(const float4*)(src + 32);
  const float4 u3 = *(const float4*)(src + 36);
  bf16x8 a0, a1;
  a0[0] = (short)f2bf(u0.x); a0[1] = (short)f2bf(u0.y);
  a0[2] = (short)f2bf(u0.z); a0[3] = (short)f2bf(u0.w);
  a0[4] = (short)f2bf(u1.x); a0[5] = (short)f2bf(u1.y);
  a0[6] = (short)f2bf(u1.z); a0[7] = (short)f2bf(u1.w);
  a1[0] = (short)f2bf(u2.x); a1[1] = (short)f2bf(u2.y);
  a1[2] = (short)f2bf(u2.z); a1[3] = (short)f2bf(u2.w);
  a1[4] = (short)f2bf(u3.x); a1[5] = (short)f2bf(u3.y);
  a1[6] = (short)f2bf(u3.z); a1[7] = (short)f2bf(u3.w);

  float linv[4][4];
#pragma unroll
  for (int nt = 0; nt < 4; nt++) {
    const float blv = bl[nt * 16 + l15];
    f32x4 acc = (f32x4){blv, blv, blv, blv};
    acc = __builtin_amdgcn_mfma_f32_16x16x32_bf16(a0, wp[(((0 * 4 + nt) * 2 + 0) << 6) + lane], acc, 0, 0, 0);
    acc = __builtin_amdgcn_mfma_f32_16x16x32_bf16(a1, wp[(((0 * 4 + nt) * 2 + 1) << 6) + lane], acc, 0, 0, 0);
#pragma unroll
    for (int r = 0; r < 4; r++) linv[nt][r] = acc[r];
  }
#pragma unroll
  for (int nt = 0; nt < 4; nt++) {
    const float bgv = bg[nt * 16 + l15];
    f32x4 acc = (f32x4){bgv, bgv, bgv, bgv};
    acc = __builtin_amdgcn_mfma_f32_16x16x32_bf16(a0, wp[(((2 * 4 + nt) * 2 + 0) << 6) + lane], acc, 0, 0, 0);
    acc = __builtin_amdgcn_mfma_f32_16x16x32_bf16(a1, wp[(((2 * 4 + nt) * 2 + 1) << 6) + lane], acc, 0, 0, 0);
#pragma unroll
    for (int r = 0; r < 4; r++) {
      const int atom = mbase + kg * 4 + r;
      if (atom < N)
        glpk8[(size_t)atom * H + nt * 16 + l15] = pack_gl8(acc[r], linv[nt][r]);
    }
  }
#pragma unroll
  for (int nt = 0; nt < 4; nt++) {
    f32x4 acc = (f32x4){0.f, 0.f, 0.f, 0.f};
    acc = __builtin_amdgcn_mfma_f32_16x16x32_bf16(a0, wp[(((1 * 4 + nt) * 2 + 0) << 6) + lane], acc, 0, 0, 0);
    acc = __builtin_amdgcn_mfma_f32_16x16x32_bf16(a1, wp[(((1 * 4 + nt) * 2 + 1) << 6) + lane], acc, 0, 0, 0);
#pragma unroll
    for (int r = 0; r < 4; r++) {
      const int atom = mbase + kg * 4 + r;
      if (atom < N) gr[(size_t)atom * H + nt * 16 + l15] = acc[r];
    }
  }
}

// ---------- mmx: x(bf16) -> gr(f32)/glpk8; per-mat loop ----------
__global__ __launch_bounds__(256) void node_mmx_mfma(
    const ushort* __restrict__ x, const bf16x8* __restrict__ wp,
    const float* __restrict__ bl, const float* __restrict__ bg,
    float* __restrict__ gr, ushort* __restrict__ glpk8, int N) {
  const int tid = threadIdx.x;
  const int lane = tid & 63, wid = tid >> 6;
  const int l15 = lane & 15, kg = lane >> 4;
  const int mbase = blockIdx.x * 64 + wid * 16;
  const int arow_c = min(mbase + l15, N - 1);
  const ushort* src = x + (size_t)arow_c * H + kg * 8;
  const bf16x8 a0 = *(const bf16x8*)(src);
  const bf16x8 a1 = *(const bf16x8*)(src + 32);

  float linv[4][4];
#pragma unroll
  for (int nt = 0; nt < 4; nt++) {
    const float blv = bl[nt * 16 + l15];
    f32x4 acc = (f32x4){blv, blv, blv, blv};
    acc = __builtin_amdgcn_mfma_f32_16x16x32_bf16(a0, wp[(((0 * 4 + nt) * 2 + 0) << 6) + lane], acc, 0, 0, 0);
    acc = __builtin_amdgcn_mfma_f32_16x16x32_bf16(a1, wp[(((0 * 4 + nt) * 2 + 1) << 6) + lane], acc, 0, 0, 0);
#pragma unroll
    for (int r = 0; r < 4; r++) linv[nt][r] = acc[r];
  }
#pragma unroll
  for (int nt = 0; nt < 4; nt++) {
    const float bgv = bg[nt * 16 + l15];
    f32x4 acc = (f32x4){bgv, bgv, bgv, bgv};
    acc = __builtin_amdgcn_mfma_f32_16x16x32_bf16(a0, wp[(((2 * 4 + nt) * 2 + 0) << 6) + lane], acc, 0, 0, 0);
    acc = __builtin_amdgcn_mfma_f32_16x16x32_bf16(a1, wp[(((2 * 4 + nt) * 2 + 1) << 6) + lane], acc, 0, 0, 0);
#pragma unroll
    for (int r = 0; r < 4; r++) {
      const int atom = mbase + kg * 4 + r;
      if (atom < N)
        glpk8[(size_t)atom * H + nt * 16 + l15] = pack_gl8(acc[r], linv[nt][r]);
    }
  }
#pragma unroll
  for (int nt = 0; nt < 4; nt++) {
    f32x4 acc = (f32x4){0.f, 0.f, 0.f, 0.f};
    acc = __builtin_amdgcn_mfma_f32_16x16x32_bf16(a0, wp[(((1 * 4 + nt) * 2 + 0) << 6) + lane], acc, 0, 0, 0);
    acc = __builtin_amdgcn_mfma_f32_16x16x32_bf16(a1, wp[(((1 * 4 + nt) * 2 + 1) << 6) + lane], acc, 0, 0, 0);
#pragma unroll
    for (int r = 0; r < 4; r++) {
      const int atom = mbase + kg * 4 + r;
      if (atom < N) gr[(size_t)atom * H + nt * 16 + l15] = acc[r];
    }
  }
}

// ---------- aggregate + update: R12 structure, fp8 payload ----------
__global__ __launch_bounds__(256) void agg_kernel(
    const float* __restrict__ gr, const ushort* __restrict__ glpk8,
    const int* __restrict__ offs, const int* __restrict__ cols,
    ushort* __restrict__ x, int N) {
  const int lane = threadIdx.x & 63, w = threadIdx.x >> 6;
  for (int i = blockIdx.x * 4 + w; i < N; i += gridDim.x * 4) {
    const int s = offs[i], e = offs[i + 1];
    const float gri = gr[(size_t)i * H + lane];
    float acc = 0.f;
    for (int cb = s; cb < e; cb += 64) {
      const int nchunk = min(64, e - cb);
      const int myc = (lane < nchunk) ? cols[cb + lane] : 0;
      int j = 0;
      for (; j + 3 < nchunk; j += 4) {
        const int c0 = __shfl(myc, j + 0), c1 = __shfl(myc, j + 1);
        const int c2 = __shfl(myc, j + 2), c3 = __shfl(myc, j + 3);
        const ushort p0 = glpk8[(size_t)c0 * H + lane];
        const ushort p1 = glpk8[(size_t)c1 * H + lane];
        const ushort p2 = glpk8[(size_t)c2 * H + lane];
        const ushort p3 = glpk8[(size_t)c3 * H + lane];
        acc += unpack_lin8(p0) * sigmoidf_fast(gri + unpack_gc8(p0));
        acc += unpack_lin8(p1) * sigmoidf_fast(gri + unpack_gc8(p1));
        acc += unpack_lin8(p2) * sigmoidf_fast(gri + unpack_gc8(p2));
        acc += unpack_lin8(p3) * sigmoidf_fast(gri + unpack_gc8(p3));
      }
      for (; j < nchunk; j++) {
        const int c0 = __shfl(myc, j);
        const ushort p0 = glpk8[(size_t)c0 * H + lane];
        acc += unpack_lin8(p0) * sigmoidf_fast(gri + unpack_gc8(p0));
      }
    }
    const float li = unpack_lin8(glpk8[(size_t)i * H + lane]);
    x[(size_t)i * H + lane] = f2bf(fmaxf(acc + li, 0.f));
  }
}

// ---------- mean pool (bf16 x), verbatim ----------
__global__ void pool_kernel(const ushort* __restrict__ x,
                            float* __restrict__ pool, int N) {
  __shared__ float ps[4][64];
  const int tid = threadIdx.x, c = tid & 63, wid = tid >> 6;
  float s = 0.f;
  for (int i = blockIdx.x * 4 + wid; i < N; i += gridDim.x * 4)
    s += __uint_as_float(((uint32_t)x[(size_t)i * H + c]) << 16);
  ps[wid][c] = s;
  __syncthreads();
  if (tid < 64) {
    const float t = ps[0][tid] + ps[1][tid] + ps[2][tid] + ps[3][tid];
    atomicAdd(&pool[tid], t);
  }
}

// ---------- final MLP ----------
__global__ void mlp_kernel(const float* __restrict__ pool,
                           const float* __restrict__ W1,
                           const float* __restrict__ b1,
                           const float* __restrict__ W2,
                           const float* __restrict__ b2,
                           float* __restrict__ out, float invN) {
  __shared__ float p[64], h[64];
  const int tid = threadIdx.x;
  if (tid < 64) p[tid] = pool[tid] * invN;
  __syncthreads();
  if (tid < 64) {
    float s = b1[tid];
    for (int k = 0; k < 64; k++) s = fmaf(p[k], W1[k * 64 + tid], s);
    h[tid] = fmaxf(s, 0.f);
  }
  __syncthreads();
  float s = b2[tid];
  for (int k = 0; k < 64; k++) s = fmaf(h[k], W2[k * 128 + tid], s);
  out[tid] = s;
}

extern "C" void kernel_launch(void* const* d_in, const int* in_sizes, int n_in,
                              void* d_out, int out_size, void* d_ws,
                              size_t ws_size, hipStream_t stream) {
  const int*   an  = (const int*)d_in[0];
  const int*   ei  = (const int*)d_in[3];
  const float* emb = (const float*)d_in[4];
  const float* Wl  = (const float*)d_in[5];
  const float* bl  = (const float*)d_in[6];
  const float* Wg  = (const float*)d_in[7];
  const float* bg  = (const float*)d_in[8];
  const float* W1  = (const float*)d_in[9];
  const float* b1  = (const float*)d_in[10];
  const float* W2  = (const float*)d_in[11];
  const float* b2  = (const float*)d_in[12];
  float* out = (float*)d_out;

  const int N = in_sizes[0];
  const int E = in_sizes[3] / 2;
  const int* row = ei;
  const int* col = ei + E;
  const int nbuck = (N + BROWS - 1) >> BSHIFT;

  const size_t NH = (size_t)N * H;
  char* ws = (char*)d_ws;
  float*  gr    = (float*)(ws);                // f32 [N][64]
  ushort* glpk8 = (ushort*)(ws + NH * 4);      // u16 [N][64]  (fp8 gc|lin)
  ushort* x     = (ushort*)(ws + NH * 4 + NH * 2);  // bf16 [N][64]
  char* p = ws + NH * 4 + NH * 2 + NH * 2;
  uint32_t* ebuf   = (uint32_t*)p; p += (size_t)E * 4;
  int*      cols   = (int*)p;      p += (size_t)E * 4;
  int*      offs   = (int*)p;      p += ((size_t)N + 1) * 4;
  int*      bcnt   = (int*)p;      p += 8192;
  int*      bstart = (int*)p;      p += 8196;
  int*      bcur   = (int*)p;      p += 8192;
  bf16x8*   wprep  = (bf16x8*)p;   p += 4608 * 16;
  float*    pool   = (float*)p;
  // total ≈ 25.6 + 12.8 + 12.8 + 4 + 4 + 0.4 MB + ~100KB ≈ 60 MB

  prep_kernel<<<18, 256, 0, stream>>>(Wl, Wg, wprep, bcnt, nbuck);

  bucket_hist_kernel<<<1024, 256, 0, stream>>>(row, bcnt, E, nbuck);
  bucket_scan_kernel<<<1, 1024, 0, stream>>>(bcnt, bstart, bcur, offs, pool,
                                             nbuck, N, E);
  bucket_scatter_kernel<<<(E + SCHUNK - 1) / SCHUNK, 256, 0, stream>>>(
      row, col, bcur, ebuf, E, nbuck);
  csr_build_kernel<<<nbuck, 256, 0, stream>>>(ebuf, bstart, offs, cols, N);

  const int mmGrid = (N + 63) / 64;
  const int aggGrid = (N + 3) / 4;

  node_mm0_mfma<<<mmGrid, 256, 0, stream>>>(an, emb, wprep, bl, bg, gr, glpk8, N);
  for (int l = 0; l < 3; l++) {
    agg_kernel<<<aggGrid, 256, 0, stream>>>(gr, glpk8, offs, cols, x, N);
    if (l < 2)
      node_mmx_mfma<<<mmGrid, 256, 0, stream>>>(
          x, wprep + (size_t)(l + 1) * 1536, bl + (size_t)(l + 1) * H,
          bg + (size_t)(l + 1) * H, gr, glpk8, N);
  }

  pool_kernel<<<1024, 256, 0, stream>>>(x, pool, N);
  mlp_kernel<<<1, 128, 0, stream>>>(pool, W1, b1, W2, b2, out, 1.0f / (float)N);
}